// Round 1
// 266.029 us; speedup vs baseline: 1.7365x; 1.7365x over previous
//
#include <hip/hip_runtime.h>

#define N_TOT  200000
#define NG_    100000
#define NU_    100000
#define E_CNT  3200000
#define C_CNT  1000000

#define NBUCK  196        // ceil(NG_/512): bucket k covers nodes [k*512, k*512+512)
#define NBLK   256        // edge chunks
#define CHUNK  12500      // E_CNT / NBLK exactly

// ---- Phase A: per-(chunk,bucket) histogram, LDS-only atomics ----
__global__ __launch_bounds__(256) void phaseA(const int* __restrict__ dst,
                                              int* __restrict__ cnt_mat) {
    __shared__ int hcnt[NBUCK];
    int t = threadIdx.x;
    if (t < NBUCK) hcnt[t] = 0;
    __syncthreads();
    int beg = blockIdx.x * CHUNK, end = beg + CHUNK;
    for (int e = beg + t; e < end; e += 256)
        atomicAdd(&hcnt[dst[e] >> 9], 1);
    __syncthreads();
    if (t < NBUCK) cnt_mat[blockIdx.x * NBUCK + t] = hcnt[t];
}

// ---- Phase B1: per-column (bucket) exclusive scan over chunks ----
__global__ __launch_bounds__(256) void phaseB1(const int* __restrict__ cnt_mat,
                                               int* __restrict__ off_mat,
                                               int* __restrict__ colsum) {
    __shared__ int s[256];
    int t = threadIdx.x;          // chunk index
    int k = blockIdx.x;           // bucket index
    int v = cnt_mat[t * NBUCK + k];
    s[t] = v;
    __syncthreads();
    for (int off = 1; off < 256; off <<= 1) {
        int u = (t >= off) ? s[t - off] : 0;
        __syncthreads();
        s[t] += u;
        __syncthreads();
    }
    off_mat[t * NBUCK + k] = s[t] - v;     // exclusive within column
    if (t == 255) colsum[k] = s[255];
}

// ---- Phase B2: exclusive scan of bucket totals -> bbase[0..NBUCK] ----
__global__ __launch_bounds__(256) void phaseB2(const int* __restrict__ colsum,
                                               int* __restrict__ bbase) {
    __shared__ int s[256];
    int t = threadIdx.x;
    int v = (t < NBUCK) ? colsum[t] : 0;
    s[t] = v;
    __syncthreads();
    for (int off = 1; off < 256; off <<= 1) {
        int u = (t >= off) ? s[t - off] : 0;
        __syncthreads();
        s[t] += u;
        __syncthreads();
    }
    if (t < NBUCK) bbase[t] = s[t] - v;
    if (t == NBUCK - 1) bbase[NBUCK] = s[t];
}

// ---- Phase C: bucket-scatter packed (src<<9 | bin); LDS-only atomics ----
__global__ __launch_bounds__(256) void phaseC(const int* __restrict__ src,
                                              const int* __restrict__ dst,
                                              const int* __restrict__ off_mat,
                                              const int* __restrict__ bbase,
                                              int* __restrict__ pairs) {
    __shared__ int loc[NBUCK];
    int t = threadIdx.x;
    if (t < NBUCK) loc[t] = bbase[t] + off_mat[blockIdx.x * NBUCK + t];
    __syncthreads();
    int beg = blockIdx.x * CHUNK, end = beg + CHUNK;
    for (int e = beg + t; e < end; e += 256) {
        int d = dst[e], s = src[e];
        int k = d >> 9;
        int pos = atomicAdd(&loc[k], 1);
        pairs[pos] = (s << 9) | (d & 511);
    }
}

// ---- Phase D: per-bucket counting sort -> full per-node CSR ----
// node_off[n] = start of node n's src list in csr_src; node_off[NG_] == E_CNT.
__global__ __launch_bounds__(1024) void phaseD(const int* __restrict__ bbase,
                                               const int* __restrict__ pairs,
                                               int* __restrict__ csr_src,
                                               int* __restrict__ node_off) {
    __shared__ int cnt[512], scn[512], base[512];
    int t = threadIdx.x, k = blockIdx.x;
    if (t < 512) cnt[t] = 0;
    __syncthreads();
    int beg = bbase[k], end = bbase[k + 1];
    for (int e = beg + t; e < end; e += 1024)
        atomicAdd(&cnt[pairs[e] & 511], 1);
    __syncthreads();
    if (t < 512) scn[t] = cnt[t];
    __syncthreads();
    for (int off = 1; off < 512; off <<= 1) {
        int v = 0;
        if (t < 512 && t >= off) v = scn[t - off];
        __syncthreads();
        if (t < 512) scn[t] += v;
        __syncthreads();
    }
    if (t < 512) {
        int bse = beg + scn[t] - cnt[t];     // exclusive scan -> absolute base
        base[t] = bse;
        node_off[(k << 9) + t] = bse;        // bucket 195 bins >= 160 are empty,
                                             // so node_off[100000] lands at E_CNT.
    }
    __syncthreads();
    for (int e = beg + t; e < end; e += 1024) {
        int p = pairs[e];
        int pos = atomicAdd(&base[p & 511], 1);
        csr_src[pos] = p >> 9;
    }
}

// ---- conv1: CSR register aggregation, 8 lanes per node, no atomics/LDS ----
__global__ __launch_bounds__(256) void conv1_csr(const int* __restrict__ node_off,
                                                 const int* __restrict__ csr_src,
                                                 const float* __restrict__ x,
                                                 const float* __restrict__ w_rel,
                                                 const float* __restrict__ w_root,
                                                 const float* __restrict__ b,
                                                 float* __restrict__ h1) {
    int t = threadIdx.x;
    int n = blockIdx.x * 32 + (t >> 3);     // grid 3125*32 == 100000 exactly
    int l = t & 7;
    int beg = node_off[n], end = node_off[n + 1];
    float a0 = 0.f, a1 = 0.f;
    for (int e = beg + l; e < end; e += 8) {
        int s = csr_src[e];
        float2 xv = *(const float2*)(x + 2 * s);
        a0 += xv.x; a1 += xv.y;
    }
#pragma unroll
    for (int d = 1; d < 8; d <<= 1) {
        a0 += __shfl_xor(a0, d, 64);
        a1 += __shfl_xor(a1, d, 64);
    }
    float2 xn = *(const float2*)(x + 2 * n);
    float v = a0 * w_rel[l] + a1 * w_rel[8 + l]
            + xn.x * w_root[l] + xn.y * w_root[8 + l] + b[l];
    h1[8 * n + l] = fmaxf(v, 0.f);
}

// ---- conv2: CSR register aggregation, 8 lanes per node, no atomics/LDS ----
__global__ __launch_bounds__(256) void conv2_csr(const int* __restrict__ node_off,
                                                 const int* __restrict__ csr_src,
                                                 const float* __restrict__ h1,
                                                 const float* __restrict__ w_rel,
                                                 const float* __restrict__ w_root,
                                                 const float* __restrict__ b,
                                                 float* __restrict__ h2) {
    int t = threadIdx.x;
    int n = blockIdx.x * 32 + (t >> 3);
    int l = t & 7;
    int beg = node_off[n], end = node_off[n + 1];
    float acc[8] = {0.f, 0.f, 0.f, 0.f, 0.f, 0.f, 0.f, 0.f};
    for (int e = beg + l; e < end; e += 8) {
        int s = csr_src[e];
        const float4* hp = (const float4*)(h1 + 8 * s);
        float4 v0 = hp[0], v1 = hp[1];
        acc[0] += v0.x; acc[1] += v0.y; acc[2] += v0.z; acc[3] += v0.w;
        acc[4] += v1.x; acc[5] += v1.y; acc[6] += v1.z; acc[7] += v1.w;
    }
#pragma unroll
    for (int d = 1; d < 8; d <<= 1)
#pragma unroll
        for (int j = 0; j < 8; j++)
            acc[j] += __shfl_xor(acc[j], d, 64);
    const float4* hp = (const float4*)(h1 + 8 * n);
    float4 t0 = hp[0], t1 = hp[1];
    float hn[8] = {t0.x, t0.y, t0.z, t0.w, t1.x, t1.y, t1.z, t1.w};
#pragma unroll
    for (int cc = 0; cc < 2; cc++) {
        int c = l + 8 * cc;
        float v = b[c];
#pragma unroll
        for (int j = 0; j < 8; j++)
            v += acc[j] * w_rel[j * 16 + c] + hn[j] * w_root[j * 16 + c];
        h2[16 * n + c] = fmaxf(v, 0.f);
    }
}

// ---- prep: fold wu/bu into wa's bottom half; transpose wa's top half ----
// wprep layout (floats): wT16[1024] (wT16[j*16+i] = wa[i*64+j]),
//                        wc0[64] @1024, wc1[64] @1088, bc[64] @1152
__global__ void prep_kernel(const float* __restrict__ wu,
                            const float* __restrict__ bu,
                            const float* __restrict__ wa,
                            const float* __restrict__ ba,
                            float* __restrict__ wprep) {
    int j = threadIdx.x;   // 64 threads
#pragma unroll
    for (int i = 0; i < 16; i++) wprep[j * 16 + i] = wa[i * 64 + j];
    float c0 = 0.f, c1 = 0.f, bc = ba[j];
#pragma unroll
    for (int k = 0; k < 16; k++) {
        float w = wa[(16 + k) * 64 + j];
        c0 += wu[k] * w;
        c1 += wu[16 + k] * w;
        bc += bu[k] * w;
    }
    wprep[1024 + j] = c0;
    wprep[1088 + j] = c1;
    wprep[1152 + j] = bc;
}

// ---- final MLP: uniform weights via scalar loads, folded xu projection ----
__global__ __launch_bounds__(256) void final_mlp2(const int* __restrict__ cand,
                                                  const float* __restrict__ h2,
                                                  const float* __restrict__ x,
                                                  const float* __restrict__ wprep,
                                                  const float* __restrict__ wb,
                                                  const float* __restrict__ bb,
                                                  float* __restrict__ out) {
    int c = blockIdx.x * 256 + threadIdx.x;
    if (c >= C_CNT) return;
    int g = cand[2 * c], u = cand[2 * c + 1];
    float ec[16];
    const float4* hp = (const float4*)(h2 + 16 * g);
#pragma unroll
    for (int q = 0; q < 4; q++) {
        float4 v = hp[q];
        ec[4 * q] = v.x; ec[4 * q + 1] = v.y; ec[4 * q + 2] = v.z; ec[4 * q + 3] = v.w;
    }
    float2 xv = *(const float2*)(x + 2 * (NG_ + u));
    float acc = bb[0];
#pragma unroll 4
    for (int j = 0; j < 64; j++) {
        // all weight addresses are wave-uniform -> scalar loads, SGPR operands
        float v = wprep[1152 + j] + xv.x * wprep[1024 + j] + xv.y * wprep[1088 + j];
        const float* wr = wprep + j * 16;
#pragma unroll
        for (int i = 0; i < 16; i++) v += ec[i] * wr[i];
        acc += fmaxf(v, 0.f) * wb[j];
    }
    out[c] = acc;
}

// ======================= launch =======================

extern "C" void kernel_launch(void* const* d_in, const int* in_sizes, int n_in,
                              void* d_out, int out_size, void* d_ws, size_t ws_size,
                              hipStream_t stream) {
    const float* x      = (const float*)d_in[0];
    const int*   cand   = (const int*)d_in[2];
    const int*   edges  = (const int*)d_in[3];   // [2, E]: src then dst
    const float* w1_rel = (const float*)d_in[4];
    const float* w1_root= (const float*)d_in[5];
    const float* b1     = (const float*)d_in[6];
    const float* w2_rel = (const float*)d_in[7];
    const float* w2_root= (const float*)d_in[8];
    const float* b2     = (const float*)d_in[9];
    const float* wu     = (const float*)d_in[10];
    const float* bu     = (const float*)d_in[11];
    const float* wa     = (const float*)d_in[12];
    const float* ba     = (const float*)d_in[13];
    const float* wb     = (const float*)d_in[14];
    const float* bb     = (const float*)d_in[15];
    float* out = (float*)d_out;

    const int* src = edges;
    const int* dst = edges + E_CNT;

    // ws layout (int units), ~36.0 MB total:
    //   cnt_mat  [0         .. 50,176)
    //   off_mat  [50,176    .. 100,352)
    //   colsum   [100,352   .. 100,548)
    //   bbase    [100,608   .. 100,805)
    //   node_off [100,864   .. 201,728)   (100,353 used, padded)
    //   wprep    [201,728   .. 202,944)   (1,216 floats)
    //   pairs    [202,944   .. 3,402,944)
    //   csr_src  [3,402,944 .. 6,602,944)
    //   h1 (f)   [6,602,944 .. 7,402,944)
    //   h2 (f)   [7,402,944 .. 9,002,944)
    int* ws_i = (int*)d_ws;
    int*   cnt_mat  = ws_i;
    int*   off_mat  = ws_i + 50176;
    int*   colsum   = ws_i + 100352;
    int*   bbase    = ws_i + 100608;
    int*   node_off = ws_i + 100864;
    float* wprep    = (float*)(ws_i + 201728);
    int*   pairs    = ws_i + 202944;
    int*   csr_src  = ws_i + 3402944;
    float* h1       = (float*)(ws_i + 6602944);
    float* h2       = (float*)(ws_i + 7402944);

    dim3 blk256(256);

    prep_kernel<<<1, 64, 0, stream>>>(wu, bu, wa, ba, wprep);
    phaseA <<<NBLK, blk256, 0, stream>>>(dst, cnt_mat);
    phaseB1<<<NBUCK, blk256, 0, stream>>>(cnt_mat, off_mat, colsum);
    phaseB2<<<1, blk256, 0, stream>>>(colsum, bbase);
    phaseC <<<NBLK, blk256, 0, stream>>>(src, dst, off_mat, bbase, pairs);
    phaseD <<<NBUCK, 1024, 0, stream>>>(bbase, pairs, csr_src, node_off);
    conv1_csr<<<3125, blk256, 0, stream>>>(node_off, csr_src, x, w1_rel, w1_root, b1, h1);
    conv2_csr<<<3125, blk256, 0, stream>>>(node_off, csr_src, h1, w2_rel, w2_root, b2, h2);
    final_mlp2<<<(C_CNT + 255) / 256, blk256, 0, stream>>>(cand, h2, x, wprep, wb, bb, out);
}